// Round 1
// baseline (103.335 us; speedup 1.0000x reference)
//
#include <hip/hip_runtime.h>
#include <hip/hip_bf16.h>
#include <stdint.h>

// covpool: y[b] = (1/M) * Xc[b] * Xc[b]^T,  Xc = row-centered x, B=64, dim=512, M=256.
// Pass 1 centers + scales by 1/16 (so (1/16)^2 = 1/M folds into the product) and
// converts to bf16 in d_ws. Pass 2 is a batched bf16 MFMA SYRK (m97 structure).

typedef __attribute__((ext_vector_type(8))) short bf16x8;   // 8 bf16 = 4 VGPRs
typedef __attribute__((ext_vector_type(4))) float f32x4;    // MFMA 16x16 accumulator

static __device__ __forceinline__ unsigned short f2bf(float f) {
    union { float f; uint32_t u; } c; c.f = f;
    uint32_t u = c.u;
    // round-to-nearest-even (inputs are finite; no NaN handling needed)
    return (unsigned short)((u + 0x7FFFu + ((u >> 16) & 1u)) >> 16);
}

// ---------------- Pass 1: center rows, scale 1/16, cvt bf16 ----------------
// one wave per (b,d) row of 256 floats; 4 rows per 256-thread block
__global__ __launch_bounds__(256) void center_bf16(const float* __restrict__ x,
                                                   unsigned short* __restrict__ xb) {
    const int wave = threadIdx.x >> 6;
    const int lane = threadIdx.x & 63;
    const int row  = blockIdx.x * 4 + wave;          // 0..32767
    const float4 v = ((const float4*)(x + (size_t)row * 256))[lane];
    float s = v.x + v.y + v.z + v.w;
#pragma unroll
    for (int off = 32; off > 0; off >>= 1)
        s += __shfl_xor(s, off, 64);
    const float mean = s * (1.0f / 256.0f);
    const float sc = 0.0625f;                        // 1/16
    ushort4 o;
    o.x = f2bf((v.x - mean) * sc);
    o.y = f2bf((v.y - mean) * sc);
    o.z = f2bf((v.z - mean) * sc);
    o.w = f2bf((v.w - mean) * sc);
    ((ushort4*)(xb + (size_t)row * 256))[lane] = o;
}

// ---------------- Pass 2: batched SYRK, 128x128 tile, BK=32 ----------------
static __device__ __forceinline__ void gl_lds16(const unsigned short* g, unsigned short* l) {
    __builtin_amdgcn_global_load_lds(
        (const __attribute__((address_space(1))) unsigned int*)g,
        (__attribute__((address_space(3))) unsigned int*)l,
        16, 0, 0);
}

__global__ __launch_bounds__(256) void syrk_bf16(const unsigned short* __restrict__ xb,
                                                 float* __restrict__ y) {
    __shared__ unsigned short As[128 * 32];   // bf16 bits, row-major [row][k], unpadded
    __shared__ unsigned short Bs[128 * 32];

    // XCD-aware swizzle: round-robin dispatch means blockIdx%8 -> XCD.
    // Give each XCD a contiguous group of 8 batches so each batch's 256 KB
    // xb slab is read from a single XCD's L2 (perf heuristic only).
    const int xcd  = blockIdx.x & 7;
    const int j    = blockIdx.x >> 3;        // 0..127
    const int b    = xcd * 8 + (j >> 4);     // 0..63
    const int tile = j & 15;
    const int tm = tile >> 2, tn = tile & 3;

    const unsigned short* Abase = xb + ((size_t)b * 512 + tm * 128) * 256;
    const unsigned short* Bbase = xb + ((size_t)b * 512 + tn * 128) * 256;

    const int tid  = threadIdx.x;
    const int lane = tid & 63;
    const int wave = tid >> 6;
    const int wm = (wave >> 1) * 64;         // wave's 64x64 subtile
    const int wn = (wave & 1) * 64;

    f32x4 acc[4][4] = {};

    const int rl = lane & 15;
    const int kh = (lane >> 4) * 8;          // k-offset of this lane's fragment

    for (int kk = 0; kk < 256; kk += 32) {
        __syncthreads();                     // protect LDS from prev-iter readers
#pragma unroll
        for (int t = 0; t < 2; ++t) {
            const int e   = t * 256 + tid;   // 0..511
            const int row = e >> 2;          // 0..127
            const int kq  = (e & 3) * 8;     // bf16 k offset within BK
            // LDS byte offset e*16 = wave-uniform base + lane*16 (required layout)
            gl_lds16(Abase + row * 256 + kk + kq, As + e * 8);
            gl_lds16(Bbase + row * 256 + kk + kq, Bs + e * 8);
        }
        __syncthreads();                     // compiler drains vmcnt before barrier

        bf16x8 af[4], bfr[4];
#pragma unroll
        for (int i = 0; i < 4; ++i)
            af[i] = *(const bf16x8*)(As + (wm + i * 16 + rl) * 32 + kh);
#pragma unroll
        for (int jj = 0; jj < 4; ++jj)
            bfr[jj] = *(const bf16x8*)(Bs + (wn + jj * 16 + rl) * 32 + kh);
#pragma unroll
        for (int i = 0; i < 4; ++i)
#pragma unroll
            for (int jj = 0; jj < 4; ++jj)
                acc[i][jj] = __builtin_amdgcn_mfma_f32_16x16x32_bf16(
                    af[i], bfr[jj], acc[i][jj], 0, 0, 0);
    }

    // Epilogue: C/D layout col=lane&15, row=(lane>>4)*4+reg  [verified m89/m91]
    float* ybase = y + (size_t)b * 512 * 512;
    const int rowb = tm * 128 + wm + (lane >> 4) * 4;
    const int colb = tn * 128 + wn + (lane & 15);
#pragma unroll
    for (int i = 0; i < 4; ++i) {
#pragma unroll
        for (int jj = 0; jj < 4; ++jj) {
            const int col = colb + jj * 16;
            const int r0  = rowb + i * 16;
#pragma unroll
            for (int r = 0; r < 4; ++r)
                ybase[(size_t)(r0 + r) * 512 + col] = acc[i][jj][r];
        }
    }
}

extern "C" void kernel_launch(void* const* d_in, const int* in_sizes, int n_in,
                              void* d_out, int out_size, void* d_ws, size_t ws_size,
                              hipStream_t stream) {
    const float* x = (const float*)d_in[0];
    float* yout = (float*)d_out;
    unsigned short* xb = (unsigned short*)d_ws;   // 64*512*256 bf16 = 16 MB

    // Pass 1: 32768 rows, 4 rows/block
    center_bf16<<<8192, 256, 0, stream>>>(x, xb);
    // Pass 2: 64 batches x 16 tiles
    syrk_bf16<<<1024, 256, 0, stream>>>(xb, yout);
}